// Round 2
// baseline (3613.676 us; speedup 1.0000x reference)
//
#include <hip/hip_runtime.h>
#include <hip/hip_bf16.h>

#define WPB 4  // waves per block (256 threads)

// Fused MLP encoder: out = tanh(x @ W1^T + b1) @ W2^T + b2, one wave per row.
template<int IN_F>
__global__ __launch_bounds__(256) void encoder_kernel(
    const float* __restrict__ x,
    const float* __restrict__ W1, const float* __restrict__ b1,
    const float* __restrict__ W2, const float* __restrict__ b2,
    float* __restrict__ out, int n_rows) {
  __shared__ float sW1[64 * IN_F];
  __shared__ float sW2T[64 * 64];   // sW2T[h*64+o] = W2[o][h]
  __shared__ float sb1[64];
  __shared__ float sb2[64];
  int t = threadIdx.x;
  for (int i = t; i < 64 * IN_F; i += 256) sW1[i] = W1[i];
  for (int i = t; i < 64 * 64; i += 256) {
    int o = i >> 6, h = i & 63;
    sW2T[h * 64 + o] = W2[i];
  }
  if (t < 64) { sb1[t] = b1[t]; sb2[t] = b2[t]; }
  __syncthreads();

  int wave = t >> 6, lane = t & 63;
  int row = blockIdx.x * WPB + wave;
  if (row >= n_rows) return;

  float xv[IN_F];
#pragma unroll
  for (int j = 0; j < IN_F; ++j) xv[j] = x[(size_t)row * IN_F + j];
  float h = sb1[lane];
#pragma unroll
  for (int j = 0; j < IN_F; ++j) h += sW1[lane * IN_F + j] * xv[j];
  float hid = tanhf(h);

  float o = sb2[lane];
#pragma unroll
  for (int i = 0; i < 64; ++i) {
    float broad = __shfl(hid, i, 64);
    o += sW2T[i * 64 + lane] * broad;
  }
  out[(size_t)row * 64 + lane] = o;
}

// Edge degree histogram (both directions in one pass).
__global__ __launch_bounds__(256) void degree_kernel(
    const int* __restrict__ ev, const int* __restrict__ ec,
    float* __restrict__ dv, float* __restrict__ dc, int n_edges) {
  int e = blockIdx.x * 256 + threadIdx.x;
  if (e >= n_edges) return;
  atomicAdd(&dv[ev[e]], 1.0f);
  atomicAdd(&dc[ec[e]], 1.0f);
}

// Scatter-add raw feature rows: acc[dst] += h[src]. One lane per (edge, feat).
__global__ __launch_bounds__(256) void scatter_kernel(
    const float* __restrict__ hsrc,
    const int* __restrict__ sidx, const int* __restrict__ didx,
    float* __restrict__ acc, int n_edges) {
  int tid = blockIdx.x * 256 + threadIdx.x;
  int e = tid >> 6, f = tid & 63;
  if (e >= n_edges) return;
  int s = sidx[e];
  int d = didx[e];
  atomicAdd(&acc[(size_t)d * 64 + f], hsrc[(size_t)s * 64 + f]);
}

// h = tanh(h + acc @ W^T + deg * b), in place. One wave per row.
__global__ __launch_bounds__(256) void update_kernel(
    float* __restrict__ h, const float* __restrict__ acc,
    const float* __restrict__ deg,
    const float* __restrict__ W, const float* __restrict__ b,
    int n_rows) {
  __shared__ float sWT[64 * 64];  // sWT[k*64+o] = W[o][k]
  __shared__ float sb[64];
  int t = threadIdx.x;
  for (int i = t; i < 64 * 64; i += 256) {
    int o = i >> 6, k = i & 63;
    sWT[k * 64 + o] = W[i];
  }
  if (t < 64) sb[t] = b[t];
  __syncthreads();

  int wave = t >> 6, lane = t & 63;
  int row = blockIdx.x * WPB + wave;
  if (row >= n_rows) return;

  float a = acc[(size_t)row * 64 + lane];
  float v = h[(size_t)row * 64 + lane] + sb[lane] * deg[row];
#pragma unroll
  for (int i = 0; i < 64; ++i) {
    float broad = __shfl(a, i, 64);
    v += sWT[i * 64 + lane] * broad;
  }
  h[(size_t)row * 64 + lane] = tanhf(v);
}

// scores = h_var @ W_ro^T + b_ro. One wave per row, butterfly reduce.
__global__ __launch_bounds__(256) void readout_kernel(
    const float* __restrict__ h,
    const float* __restrict__ Wro, const float* __restrict__ bro,
    float* __restrict__ out, int n_rows) {
  int t = threadIdx.x;
  int wave = t >> 6, lane = t & 63;
  int row = blockIdx.x * WPB + wave;
  if (row >= n_rows) return;
  float v = h[(size_t)row * 64 + lane] * Wro[lane];
#pragma unroll
  for (int off = 32; off > 0; off >>= 1) v += __shfl_xor(v, off, 64);
  if (lane == 0) out[row] = v + bro[0];
}

extern "C" void kernel_launch(void* const* d_in, const int* in_sizes, int n_in,
                              void* d_out, int out_size, void* d_ws, size_t ws_size,
                              hipStream_t stream) {
  const float* vf    = (const float*)d_in[0];
  const float* cf    = (const float*)d_in[1];
  const int*   ev    = (const int*)d_in[2];
  const int*   ec    = (const int*)d_in[3];
  const float* W_ve1 = (const float*)d_in[4];
  const float* b_ve1 = (const float*)d_in[5];
  const float* W_ve2 = (const float*)d_in[6];
  const float* b_ve2 = (const float*)d_in[7];
  const float* W_ce1 = (const float*)d_in[8];
  const float* b_ce1 = (const float*)d_in[9];
  const float* W_ce2 = (const float*)d_in[10];
  const float* b_ce2 = (const float*)d_in[11];
  const float* W_v2c = (const float*)d_in[12];
  const float* b_v2c = (const float*)d_in[13];
  const float* W_c2v = (const float*)d_in[14];
  const float* b_c2v = (const float*)d_in[15];
  const float* W_ro  = (const float*)d_in[16];
  const float* b_ro  = (const float*)d_in[17];

  const int n_vars  = in_sizes[0] / 7;
  const int n_cons  = in_sizes[1] / 5;
  const int n_edges = in_sizes[2];
  const int R       = in_sizes[12] / (64 * 64);

  char* p = (char*)d_ws;
  float* h_var = (float*)p; p += (size_t)n_vars * 64 * 4;
  float* h_con = (float*)p; p += (size_t)n_cons * 64 * 4;
  float* acc_v = (float*)p; p += (size_t)n_vars * 64 * 4;
  float* acc_c = (float*)p; p += (size_t)n_cons * 64 * 4;
  float* deg_v = (float*)p; p += (size_t)n_vars * 4;
  float* deg_c = (float*)p; p += (size_t)n_cons * 4;

  hipMemsetAsync(deg_v, 0, (size_t)n_vars * 4, stream);
  hipMemsetAsync(deg_c, 0, (size_t)n_cons * 4, stream);
  degree_kernel<<<(n_edges + 255) / 256, 256, 0, stream>>>(ev, ec, deg_v, deg_c, n_edges);

  encoder_kernel<7><<<(n_vars + WPB - 1) / WPB, 256, 0, stream>>>(
      vf, W_ve1, b_ve1, W_ve2, b_ve2, h_var, n_vars);
  encoder_kernel<5><<<(n_cons + WPB - 1) / WPB, 256, 0, stream>>>(
      cf, W_ce1, b_ce1, W_ce2, b_ce2, h_con, n_cons);

  const int eblocks = (int)(((long long)n_edges * 64 + 255) / 256);
  for (int r = 0; r < R; ++r) {
    // var -> con
    hipMemsetAsync(acc_c, 0, (size_t)n_cons * 64 * 4, stream);
    scatter_kernel<<<eblocks, 256, 0, stream>>>(h_var, ev, ec, acc_c, n_edges);
    update_kernel<<<(n_cons + WPB - 1) / WPB, 256, 0, stream>>>(
        h_con, acc_c, deg_c, W_v2c + (size_t)r * 64 * 64, b_v2c + (size_t)r * 64, n_cons);
    // con -> var
    hipMemsetAsync(acc_v, 0, (size_t)n_vars * 64 * 4, stream);
    scatter_kernel<<<eblocks, 256, 0, stream>>>(h_con, ec, ev, acc_v, n_edges);
    update_kernel<<<(n_vars + WPB - 1) / WPB, 256, 0, stream>>>(
        h_var, acc_v, deg_v, W_c2v + (size_t)r * 64 * 64, b_c2v + (size_t)r * 64, n_vars);
  }

  readout_kernel<<<(n_vars + WPB - 1) / WPB, 256, 0, stream>>>(
      h_var, W_ro, b_ro, (float*)d_out, n_vars);
}

// Round 3
// 1976.420 us; speedup vs baseline: 1.8284x; 1.8284x over previous
//
#include <hip/hip_runtime.h>
#include <hip/hip_bf16.h>

#define WPB 4  // waves per block (256 threads)

// Fused MLP encoder: out = tanh(x @ W1^T + b1) @ W2^T + b2.
// Grid-stride over rows; weights staged in LDS once per block.
// sW2T padded to stride 65: staging writes conflict-free, reads 2-way (free).
template<int IN_F>
__global__ __launch_bounds__(256) void encoder_kernel(
    const float* __restrict__ x,
    const float* __restrict__ W1, const float* __restrict__ b1,
    const float* __restrict__ W2, const float* __restrict__ b2,
    float* __restrict__ out, int n_rows) {
  __shared__ float sW1[64 * IN_F];
  __shared__ float sW2T[64 * 65];   // sW2T[k*65+o] = W2[o][k]
  __shared__ float sb1[64];
  __shared__ float sb2[64];
  int t = threadIdx.x;
  for (int i = t; i < 64 * IN_F; i += 256) sW1[i] = W1[i];
  for (int i = t; i < 64 * 64; i += 256) {
    int o = i >> 6, k = i & 63;
    sW2T[k * 65 + o] = W2[i];   // consecutive lanes: k consecutive -> stride 65 -> conflict-free
  }
  if (t < 64) { sb1[t] = b1[t]; sb2[t] = b2[t]; }
  __syncthreads();

  int wave = t >> 6, lane = t & 63;
  for (int row = blockIdx.x * WPB + wave; row < n_rows; row += gridDim.x * WPB) {
    float xv[IN_F];
#pragma unroll
    for (int j = 0; j < IN_F; ++j) xv[j] = x[(size_t)row * IN_F + j];
    float h = sb1[lane];
#pragma unroll
    for (int j = 0; j < IN_F; ++j) h += sW1[lane * IN_F + j] * xv[j];
    float hid = tanhf(h);

    float o = sb2[lane];
#pragma unroll
    for (int i = 0; i < 64; ++i) {
      float broad = __shfl(hid, i, 64);
      o += sW2T[i * 65 + lane] * broad;
    }
    out[(size_t)row * 64 + lane] = o;
  }
}

// Edge degree histogram (both directions in one pass).
__global__ __launch_bounds__(256) void degree_kernel(
    const int* __restrict__ ev, const int* __restrict__ ec,
    float* __restrict__ dv, float* __restrict__ dc, int n_edges) {
  int e = blockIdx.x * 256 + threadIdx.x;
  if (e >= n_edges) return;
  atomicAdd(&dv[ev[e]], 1.0f);
  atomicAdd(&dc[ec[e]], 1.0f);
}

// Scatter-add raw feature rows: acc[dst] += h[src]. One wave per edge.
__global__ __launch_bounds__(256) void scatter_kernel(
    const float* __restrict__ hsrc,
    const int* __restrict__ sidx, const int* __restrict__ didx,
    float* __restrict__ acc, int n_edges) {
  int tid = blockIdx.x * 256 + threadIdx.x;
  int e = tid >> 6, f = tid & 63;
  if (e >= n_edges) return;
  int s = sidx[e];
  int d = didx[e];
  atomicAdd(&acc[(size_t)d * 64 + f], hsrc[(size_t)s * 64 + f]);
}

// h = tanh(h + acc @ W^T + deg * b), in place. Grid-stride over rows.
__global__ __launch_bounds__(256) void update_kernel(
    float* __restrict__ h, const float* __restrict__ acc,
    const float* __restrict__ deg,
    const float* __restrict__ W, const float* __restrict__ b,
    int n_rows) {
  __shared__ float sWT[64 * 65];  // sWT[k*65+o] = W[o][k]
  __shared__ float sb[64];
  int t = threadIdx.x;
  for (int i = t; i < 64 * 64; i += 256) {
    int o = i >> 6, k = i & 63;
    sWT[k * 65 + o] = W[i];
  }
  if (t < 64) sb[t] = b[t];
  __syncthreads();

  int wave = t >> 6, lane = t & 63;
  for (int row = blockIdx.x * WPB + wave; row < n_rows; row += gridDim.x * WPB) {
    float a = acc[(size_t)row * 64 + lane];
    float v = h[(size_t)row * 64 + lane] + sb[lane] * deg[row];
#pragma unroll
    for (int i = 0; i < 64; ++i) {
      float broad = __shfl(a, i, 64);
      v += sWT[i * 65 + lane] * broad;
    }
    h[(size_t)row * 64 + lane] = tanhf(v);
  }
}

// scores = h_var @ W_ro^T + b_ro. One wave per row, butterfly reduce.
__global__ __launch_bounds__(256) void readout_kernel(
    const float* __restrict__ h,
    const float* __restrict__ Wro, const float* __restrict__ bro,
    float* __restrict__ out, int n_rows) {
  int t = threadIdx.x;
  int wave = t >> 6, lane = t & 63;
  int row = blockIdx.x * WPB + wave;
  if (row >= n_rows) return;
  float v = h[(size_t)row * 64 + lane] * Wro[lane];
#pragma unroll
  for (int off = 32; off > 0; off >>= 1) v += __shfl_xor(v, off, 64);
  if (lane == 0) out[row] = v + bro[0];
}

static inline int rowgrid(int n) {
  int want = (n + WPB - 1) / WPB;
  return want < 2048 ? want : 2048;   // ~8 blocks/CU, grid-stride beyond
}

extern "C" void kernel_launch(void* const* d_in, const int* in_sizes, int n_in,
                              void* d_out, int out_size, void* d_ws, size_t ws_size,
                              hipStream_t stream) {
  const float* vf    = (const float*)d_in[0];
  const float* cf    = (const float*)d_in[1];
  const int*   ev    = (const int*)d_in[2];
  const int*   ec    = (const int*)d_in[3];
  const float* W_ve1 = (const float*)d_in[4];
  const float* b_ve1 = (const float*)d_in[5];
  const float* W_ve2 = (const float*)d_in[6];
  const float* b_ve2 = (const float*)d_in[7];
  const float* W_ce1 = (const float*)d_in[8];
  const float* b_ce1 = (const float*)d_in[9];
  const float* W_ce2 = (const float*)d_in[10];
  const float* b_ce2 = (const float*)d_in[11];
  const float* W_v2c = (const float*)d_in[12];
  const float* b_v2c = (const float*)d_in[13];
  const float* W_c2v = (const float*)d_in[14];
  const float* b_c2v = (const float*)d_in[15];
  const float* W_ro  = (const float*)d_in[16];
  const float* b_ro  = (const float*)d_in[17];

  const int n_vars  = in_sizes[0] / 7;
  const int n_cons  = in_sizes[1] / 5;
  const int n_edges = in_sizes[2];
  const int R       = in_sizes[12] / (64 * 64);

  char* p = (char*)d_ws;
  float* h_var = (float*)p; p += (size_t)n_vars * 64 * 4;
  float* h_con = (float*)p; p += (size_t)n_cons * 64 * 4;
  float* acc_v = (float*)p; p += (size_t)n_vars * 64 * 4;
  float* acc_c = (float*)p; p += (size_t)n_cons * 64 * 4;
  float* deg_v = (float*)p; p += (size_t)n_vars * 4;
  float* deg_c = (float*)p; p += (size_t)n_cons * 4;

  hipMemsetAsync(deg_v, 0, (size_t)n_vars * 4, stream);
  hipMemsetAsync(deg_c, 0, (size_t)n_cons * 4, stream);
  degree_kernel<<<(n_edges + 255) / 256, 256, 0, stream>>>(ev, ec, deg_v, deg_c, n_edges);

  encoder_kernel<7><<<rowgrid(n_vars), 256, 0, stream>>>(
      vf, W_ve1, b_ve1, W_ve2, b_ve2, h_var, n_vars);
  encoder_kernel<5><<<rowgrid(n_cons), 256, 0, stream>>>(
      cf, W_ce1, b_ce1, W_ce2, b_ce2, h_con, n_cons);

  const int eblocks = (int)(((long long)n_edges * 64 + 255) / 256);
  for (int r = 0; r < R; ++r) {
    // var -> con
    hipMemsetAsync(acc_c, 0, (size_t)n_cons * 64 * 4, stream);
    scatter_kernel<<<eblocks, 256, 0, stream>>>(h_var, ev, ec, acc_c, n_edges);
    update_kernel<<<rowgrid(n_cons), 256, 0, stream>>>(
        h_con, acc_c, deg_c, W_v2c + (size_t)r * 64 * 64, b_v2c + (size_t)r * 64, n_cons);
    // con -> var
    hipMemsetAsync(acc_v, 0, (size_t)n_vars * 64 * 4, stream);
    scatter_kernel<<<eblocks, 256, 0, stream>>>(h_con, ec, ev, acc_v, n_edges);
    update_kernel<<<rowgrid(n_vars), 256, 0, stream>>>(
        h_var, acc_v, deg_v, W_c2v + (size_t)r * 64 * 64, b_c2v + (size_t)r * 64, n_vars);
  }

  readout_kernel<<<(n_vars + WPB - 1) / WPB, 256, 0, stream>>>(
      h_var, W_ro, b_ro, (float*)d_out, n_vars);
}

// Round 4
// 1709.225 us; speedup vs baseline: 2.1142x; 1.1563x over previous
//
#include <hip/hip_runtime.h>
#include <hip/hip_bf16.h>

#define WPB 4          // waves per block (256 threads)
#define SCAN_EPB 1024  // elements per scan block (256 thr x 4)

// ---------------- encoders ----------------
// out = tanh(x @ W1^T + b1) @ W2^T + b2. Grid-stride; weights in LDS once/block.
template<int IN_F>
__global__ __launch_bounds__(256) void encoder_kernel(
    const float* __restrict__ x,
    const float* __restrict__ W1, const float* __restrict__ b1,
    const float* __restrict__ W2, const float* __restrict__ b2,
    float* __restrict__ out, int n_rows) {
  __shared__ float sW1[64 * IN_F];
  __shared__ float sW2T[64 * 65];   // sW2T[k*65+o] = W2[o][k]
  __shared__ float sb1[64];
  __shared__ float sb2[64];
  int t = threadIdx.x;
  for (int i = t; i < 64 * IN_F; i += 256) sW1[i] = W1[i];
  for (int i = t; i < 64 * 64; i += 256) {
    int o = i >> 6, k = i & 63;
    sW2T[k * 65 + o] = W2[i];
  }
  if (t < 64) { sb1[t] = b1[t]; sb2[t] = b2[t]; }
  __syncthreads();

  int wave = t >> 6, lane = t & 63;
  for (int row = blockIdx.x * WPB + wave; row < n_rows; row += gridDim.x * WPB) {
    float xv[IN_F];
#pragma unroll
    for (int j = 0; j < IN_F; ++j) xv[j] = x[(size_t)row * IN_F + j];
    float h = sb1[lane];
#pragma unroll
    for (int j = 0; j < IN_F; ++j) h += sW1[lane * IN_F + j] * xv[j];
    float hid = tanhf(h);

    float o = sb2[lane];
#pragma unroll
    for (int i = 0; i < 64; ++i) o += sW2T[i * 65 + lane] * __shfl(hid, i, 64);
    out[(size_t)row * 64 + lane] = o;
  }
}

// ---------------- CSR build ----------------
__global__ __launch_bounds__(256) void hist_kernel(
    const int* __restrict__ ev, const int* __restrict__ ec,
    int* __restrict__ cur_v, int* __restrict__ cur_c, int n_edges) {
  int e = blockIdx.x * 256 + threadIdx.x;
  if (e >= n_edges) return;
  atomicAdd(&cur_v[ev[e]], 1);
  atomicAdd(&cur_c[ec[e]], 1);
}

// exclusive scan, level 1: per-block (1024 elems), emits block sums
__global__ __launch_bounds__(256) void scan_blocks_kernel(
    const int* __restrict__ in, int* __restrict__ out,
    int* __restrict__ bsums, int n) {
  __shared__ int s[256];
  int t = threadIdx.x;
  int base = blockIdx.x * SCAN_EPB + t * 4;
  int v[4]; int local = 0;
#pragma unroll
  for (int j = 0; j < 4; ++j) {
    int idx = base + j;
    v[j] = (idx < n) ? in[idx] : 0;
    local += v[j];
  }
  s[t] = local;
  __syncthreads();
  for (int off = 1; off < 256; off <<= 1) {
    int val = (t >= off) ? s[t - off] : 0;
    __syncthreads();
    s[t] += val;
    __syncthreads();
  }
  int run = s[t] - local;
#pragma unroll
  for (int j = 0; j < 4; ++j) {
    int idx = base + j;
    if (idx < n) out[idx] = run;
    run += v[j];
  }
  if (t == 255) bsums[blockIdx.x] = s[255];
}

// level 2: exclusive scan of block sums in-place (single block, nb <= 1024)
__global__ __launch_bounds__(256) void scan_sums_kernel(int* __restrict__ bsums, int nb) {
  __shared__ int s[256];
  int t = threadIdx.x;
  int base = t * 4;
  int v[4]; int local = 0;
#pragma unroll
  for (int j = 0; j < 4; ++j) {
    int idx = base + j;
    v[j] = (idx < nb) ? bsums[idx] : 0;
    local += v[j];
  }
  s[t] = local;
  __syncthreads();
  for (int off = 1; off < 256; off <<= 1) {
    int val = (t >= off) ? s[t - off] : 0;
    __syncthreads();
    s[t] += val;
    __syncthreads();
  }
  int run = s[t] - local;
#pragma unroll
  for (int j = 0; j < 4; ++j) {
    int idx = base + j;
    if (idx < nb) bsums[idx] = run;
    run += v[j];
  }
}

// level 3: add scanned block offsets; also set tail rp[n] = total
__global__ __launch_bounds__(256) void scan_add_kernel(
    int* __restrict__ out, const int* __restrict__ bsums, int n, int total) {
  int t = threadIdx.x;
  int base = blockIdx.x * SCAN_EPB + t * 4;
  int add = bsums[blockIdx.x];
#pragma unroll
  for (int j = 0; j < 4; ++j) {
    int idx = base + j;
    if (idx < n) out[idx] += add;
  }
  if (blockIdx.x == 0 && t == 0) out[n] = total;
}

// placement: esrc_c[pos] = var source for con-dest CSR, and vice versa
__global__ __launch_bounds__(256) void place_kernel(
    const int* __restrict__ ev, const int* __restrict__ ec,
    const int* __restrict__ rp_v, const int* __restrict__ rp_c,
    int* __restrict__ cur_v, int* __restrict__ cur_c,
    int* __restrict__ esrc_v, int* __restrict__ esrc_c, int n_edges) {
  int e = blockIdx.x * 256 + threadIdx.x;
  if (e >= n_edges) return;
  int v = ev[e], c = ec[e];
  int pc = rp_c[c] + atomicAdd(&cur_c[c], 1);
  esrc_c[pc] = v;
  int pv = rp_v[v] + atomicAdd(&cur_v[v], 1);
  esrc_v[pv] = c;
}

// ---------------- fused aggregate + linear + tanh (+ optional readout) ----------------
// hdst[i] = tanh(hdst[i] + (sum_{e->i} hsrc[src(e)]) @ W^T + deg_i * b)
// If RO: instead of storing hdst, compute scores[i] = h . Wro + bro.
template<bool RO>
__global__ __launch_bounds__(256) void fused_update_kernel(
    float* __restrict__ hdst, const float* __restrict__ hsrc,
    const int* __restrict__ rp, const int* __restrict__ esrc,
    const float* __restrict__ W, const float* __restrict__ b,
    const float* __restrict__ Wro, const float* __restrict__ bro,
    float* __restrict__ scores, int n_rows) {
  __shared__ float sWT[64 * 65];  // sWT[k*65+o] = W[o][k]
  __shared__ float sb[64];
  __shared__ float sWro[64];
  int t = threadIdx.x;
  for (int i = t; i < 64 * 64; i += 256) {
    int o = i >> 6, k = i & 63;
    sWT[k * 65 + o] = W[i];
  }
  if (t < 64) { sb[t] = b[t]; if (RO) sWro[t] = Wro[t]; }
  __syncthreads();

  int wave = t >> 6, lane = t & 63;
  float brov = RO ? bro[0] : 0.0f;
  for (int row = blockIdx.x * WPB + wave; row < n_rows; row += gridDim.x * WPB) {
    int beg = rp[row], end = rp[row + 1];
    float acc = 0.0f;
    int p = beg;
    int sn = (p < end) ? esrc[p] : 0;
    for (; p < end; ++p) {
      int s = sn;
      sn = (p + 1 < end) ? esrc[p + 1] : 0;
      acc += hsrc[(size_t)s * 64 + lane];
    }
    float v = hdst[(size_t)row * 64 + lane] + sb[lane] * (float)(end - beg);
#pragma unroll
    for (int i = 0; i < 64; ++i) v += sWT[i * 65 + lane] * __shfl(acc, i, 64);
    float hv = tanhf(v);
    if (RO) {
      float rv = hv * sWro[lane];
#pragma unroll
      for (int off = 32; off > 0; off >>= 1) rv += __shfl_xor(rv, off, 64);
      if (lane == 0) scores[row] = rv + brov;
    } else {
      hdst[(size_t)row * 64 + lane] = hv;
    }
  }
}

static inline int rowgrid(int n) {
  int want = (n + WPB - 1) / WPB;
  return want < 2048 ? want : 2048;
}

extern "C" void kernel_launch(void* const* d_in, const int* in_sizes, int n_in,
                              void* d_out, int out_size, void* d_ws, size_t ws_size,
                              hipStream_t stream) {
  const float* vf    = (const float*)d_in[0];
  const float* cf    = (const float*)d_in[1];
  const int*   ev    = (const int*)d_in[2];
  const int*   ec    = (const int*)d_in[3];
  const float* W_ve1 = (const float*)d_in[4];
  const float* b_ve1 = (const float*)d_in[5];
  const float* W_ve2 = (const float*)d_in[6];
  const float* b_ve2 = (const float*)d_in[7];
  const float* W_ce1 = (const float*)d_in[8];
  const float* b_ce1 = (const float*)d_in[9];
  const float* W_ce2 = (const float*)d_in[10];
  const float* b_ce2 = (const float*)d_in[11];
  const float* W_v2c = (const float*)d_in[12];
  const float* b_v2c = (const float*)d_in[13];
  const float* W_c2v = (const float*)d_in[14];
  const float* b_c2v = (const float*)d_in[15];
  const float* W_ro  = (const float*)d_in[16];
  const float* b_ro  = (const float*)d_in[17];

  const int n_vars  = in_sizes[0] / 7;
  const int n_cons  = in_sizes[1] / 5;
  const int n_edges = in_sizes[2];
  const int R       = in_sizes[12] / (64 * 64);

  char* p = (char*)d_ws;
  float* h_var  = (float*)p; p += (size_t)n_vars * 64 * 4;
  float* h_con  = (float*)p; p += (size_t)n_cons * 64 * 4;
  int*   rp_v   = (int*)p;   p += (size_t)(n_vars + 1) * 4;
  int*   rp_c   = (int*)p;   p += (size_t)(n_cons + 1) * 4;
  int*   cur_v  = (int*)p;   p += (size_t)n_vars * 4;
  int*   cur_c  = (int*)p;   p += (size_t)n_cons * 4;
  int*   esrc_v = (int*)p;   p += (size_t)n_edges * 4;  // sources (cons) for var-dest CSR
  int*   esrc_c = (int*)p;   p += (size_t)n_edges * 4;  // sources (vars) for con-dest CSR
  int*   bsums  = (int*)p;   p += 1024 * 4;

  const int nb_v = (n_vars + SCAN_EPB - 1) / SCAN_EPB;
  const int nb_c = (n_cons + SCAN_EPB - 1) / SCAN_EPB;

  // 1) degree histograms
  hipMemsetAsync(cur_v, 0, (size_t)n_vars * 4, stream);
  hipMemsetAsync(cur_c, 0, (size_t)n_cons * 4, stream);
  hist_kernel<<<(n_edges + 255) / 256, 256, 0, stream>>>(ev, ec, cur_v, cur_c, n_edges);

  // 2) exclusive scans -> row pointers (tail set to n_edges)
  scan_blocks_kernel<<<nb_v, 256, 0, stream>>>(cur_v, rp_v, bsums, n_vars);
  scan_sums_kernel<<<1, 256, 0, stream>>>(bsums, nb_v);
  scan_add_kernel<<<nb_v, 256, 0, stream>>>(rp_v, bsums, n_vars, n_edges);
  scan_blocks_kernel<<<nb_c, 256, 0, stream>>>(cur_c, rp_c, bsums, n_cons);
  scan_sums_kernel<<<1, 256, 0, stream>>>(bsums, nb_c);
  scan_add_kernel<<<nb_c, 256, 0, stream>>>(rp_c, bsums, n_cons, n_edges);

  // 3) edge placement
  hipMemsetAsync(cur_v, 0, (size_t)n_vars * 4, stream);
  hipMemsetAsync(cur_c, 0, (size_t)n_cons * 4, stream);
  place_kernel<<<(n_edges + 255) / 256, 256, 0, stream>>>(
      ev, ec, rp_v, rp_c, cur_v, cur_c, esrc_v, esrc_c, n_edges);

  // 4) encoders
  encoder_kernel<7><<<rowgrid(n_vars), 256, 0, stream>>>(
      vf, W_ve1, b_ve1, W_ve2, b_ve2, h_var, n_vars);
  encoder_kernel<5><<<rowgrid(n_cons), 256, 0, stream>>>(
      cf, W_ce1, b_ce1, W_ce2, b_ce2, h_con, n_cons);

  // 5) message-passing rounds (final c->v pass fuses the readout)
  for (int r = 0; r < R; ++r) {
    fused_update_kernel<false><<<rowgrid(n_cons), 256, 0, stream>>>(
        h_con, h_var, rp_c, esrc_c,
        W_v2c + (size_t)r * 64 * 64, b_v2c + (size_t)r * 64,
        nullptr, nullptr, nullptr, n_cons);
    if (r == R - 1) {
      fused_update_kernel<true><<<rowgrid(n_vars), 256, 0, stream>>>(
          h_var, h_con, rp_v, esrc_v,
          W_c2v + (size_t)r * 64 * 64, b_c2v + (size_t)r * 64,
          W_ro, b_ro, (float*)d_out, n_vars);
    } else {
      fused_update_kernel<false><<<rowgrid(n_vars), 256, 0, stream>>>(
          h_var, h_con, rp_v, esrc_v,
          W_c2v + (size_t)r * 64 * 64, b_c2v + (size_t)r * 64,
          nullptr, nullptr, nullptr, n_vars);
    }
  }
}